// Round 5
// baseline (2948.921 us; speedup 1.0000x reference)
//
#include <hip/hip_runtime.h>
#include <math.h>

#define BB 256
#define SS 2048
#define EE 64
#define HH 128
#define MB 16              // batches per block (MFMA N)
#define NB (BB / MB)       // grid = 16 blocks
#define LROW 136           // padded f16 row length: b128 reads perfectly bank-balanced

typedef _Float16 f16x8 __attribute__((ext_vector_type(8)));
typedef _Float16 f16x4 __attribute__((ext_vector_type(4)));
typedef float f32x4 __attribute__((ext_vector_type(4)));

#if defined(__has_builtin)
#if __has_builtin(__builtin_amdgcn_exp2f)
#define EXP2F(x) __builtin_amdgcn_exp2f(x)
#else
#define EXP2F(x) exp2f(x)
#endif
#if __has_builtin(__builtin_amdgcn_rcpf)
#define RCPF(x) __builtin_amdgcn_rcpf(x)
#else
#define RCPF(x) (1.0f / (x))
#endif
#else
#define EXP2F(x) exp2f(x)
#define RCPF(x) (1.0f / (x))
#endif

__device__ __forceinline__ float sigm_f(float x) {
    float e = EXP2F(-1.442695041f * x);
    return RCPF(1.0f + e);
}
__device__ __forceinline__ float tanh_f(float x) {
    float e = EXP2F(2.885390082f * x);
    return 1.0f - 2.0f * RCPF(1.0f + e);
}

__device__ __forceinline__ f32x4 mfma16(f16x8 a, f16x8 b, f32x4 c) {
    return __builtin_amdgcn_mfma_f32_16x16x32_f16(a, b, c, 0, 0, 0);
}

__device__ __forceinline__ f16x8 pack8(float4 a, float4 b) {
    f16x8 r;
    r[0] = (_Float16)a.x; r[1] = (_Float16)a.y;
    r[2] = (_Float16)a.z; r[3] = (_Float16)a.w;
    r[4] = (_Float16)b.x; r[5] = (_Float16)b.y;
    r[6] = (_Float16)b.z; r[7] = (_Float16)b.w;
    return r;
}

// Grid = 16 blocks x 512 threads (8 waves); block = batches [16*blk,+16),
// wave w = units [16w,+16).
// MFMA roles SWAPPED vs R3: A = weights (row=unit), B = state (col=batch).
//   D[row=unit 4Q+i][col=batch l&15]  ->  lane owns 4 CONSECUTIVE units of one
//   batch: h/c write = ONE ds_write_b64 each (vs 8 scatter b16 in R3).
//   B-frag h/c read = contiguous b128 from sh[batch][unit] (bank-balanced).
//   x B-frag comes straight from global (contiguous 8 floats/lane), 2-step
//   register prefetch; dt = 1 scalar/lane. Per step/wave: 8 ds_read_b128 +
//   2 ds_write_b64 + 28 MFMA + lane-local trans epilogue. f32 cell state in
//   registers (lane owns same (batch,4 units) every step).
__global__ __launch_bounds__(512, 2) void tlstm_mfma3_kernel(
    const float* __restrict__ inputs,        // [B,S,E]
    const float* __restrict__ time_interval, // [B,S]
    const float* __restrict__ W_all,         // [4H,H]
    const float* __restrict__ b_all,         // [4H]
    const float* __restrict__ U_all,         // [4H,E]
    const float* __restrict__ b_u,           // [4H]
    const float* __restrict__ W_d,           // [H,H]
    const float* __restrict__ b_d,           // [H]
    const float* __restrict__ W_out,         // [1,H]
    const float* __restrict__ b_out,         // [1]
    float* __restrict__ out)                 // [B]
{
    const int t    = threadIdx.x;
    const int l    = t & 63;
    const int w    = t >> 6;         // wave 0..7 -> units [16w, 16w+16)
    const int bcol = l & 15;         // batch (B/C col)
    const int Q    = l >> 4;         // lane quarter -> k-slice / unit-subrow
    const int b0   = blockIdx.x * MB;

    __shared__ __align__(16) _Float16 sh_h[2][MB * LROW];  // [batch][unit]
    __shared__ __align__(16) _Float16 sh_c[2][MB * LROW];
    __shared__ float sh_red[8][4][16];

    // ---- loop-invariant weights as A-fragments (f16, registers) ----
    // A-frag: lane l holds A[row = l&15][k = (l>>4)*8 + j]  (j=0..7)
    f16x8 wA[4][4];   // [gate][k-tile]: W_all[q*H + 16w + bcol][8Q + 32kk + j]
    f16x8 uA[4][2];   // U_all[q*H + 16w + bcol][8Q + 32kk + j]
    f16x8 dA[4];      // W_d [16w + bcol][8Q + 32kk + j]
    #pragma unroll
    for (int q = 0; q < 4; ++q) {
        const float* wp = W_all + (size_t)(q * HH + 16 * w + bcol) * HH + 8 * Q;
        #pragma unroll
        for (int kk = 0; kk < 4; ++kk) {
            const float4* p = (const float4*)(wp + kk * 32);
            wA[q][kk] = pack8(p[0], p[1]);
        }
        const float* up = U_all + (size_t)(q * HH + 16 * w + bcol) * EE + 8 * Q;
        #pragma unroll
        for (int kk = 0; kk < 2; ++kk) {
            const float4* p = (const float4*)(up + kk * 32);
            uA[q][kk] = pack8(p[0], p[1]);
        }
    }
    {
        const float* dp = W_d + (size_t)(16 * w + bcol) * HH + 8 * Q;
        #pragma unroll
        for (int kk = 0; kk < 4; ++kk) {
            const float4* p = (const float4*)(dp + kk * 32);
            dA[kk] = pack8(p[0], p[1]);
        }
    }
    // ---- per-lane biases for owned units 16w + 4Q + {0..3} ----
    const int u4 = 16 * w + 4 * Q;
    float4 bs0, bs1, bs2, bs3, bd4, wo4;
    {
        float4 ba, bu;
        ba = *(const float4*)(b_all + 0 * HH + u4); bu = *(const float4*)(b_u + 0 * HH + u4);
        bs0 = make_float4(ba.x + bu.x, ba.y + bu.y, ba.z + bu.z, ba.w + bu.w);
        ba = *(const float4*)(b_all + 1 * HH + u4); bu = *(const float4*)(b_u + 1 * HH + u4);
        bs1 = make_float4(ba.x + bu.x, ba.y + bu.y, ba.z + bu.z, ba.w + bu.w);
        ba = *(const float4*)(b_all + 2 * HH + u4); bu = *(const float4*)(b_u + 2 * HH + u4);
        bs2 = make_float4(ba.x + bu.x, ba.y + bu.y, ba.z + bu.z, ba.w + bu.w);
        ba = *(const float4*)(b_all + 3 * HH + u4); bu = *(const float4*)(b_u + 3 * HH + u4);
        bs3 = make_float4(ba.x + bu.x, ba.y + bu.y, ba.z + bu.z, ba.w + bu.w);
        bd4 = *(const float4*)(b_d + u4);
        wo4 = *(const float4*)(W_out + u4);
    }

    // ---- per-lane global pointers ----
    const float* xgb = inputs + (size_t)(b0 + bcol) * SS * EE + 8 * Q;  // x[batch][8Q..]
    const float* dpt = time_interval + (size_t)(b0 + bcol) * SS;

    const int roff = bcol * LROW + 8 * Q;     // B-frag read base (+32*kk)
    const int woff = bcol * LROW + u4;        // C-write base (b64-aligned)

    // ---- prologue: zero state buf0, prime x/dt pipelines ----
    for (int i = t; i < MB * LROW; i += 512) {
        sh_h[0][i] = (_Float16)0.f;
        sh_c[0][i] = (_Float16)0.f;
    }
    f16x8 xB0, xB1;
    {
        const float4* p = (const float4*)(xgb);
        xB0 = pack8(p[0], p[1]);
        const float4* p2 = (const float4*)(xgb + 32);
        xB1 = pack8(p2[0], p2[1]);
    }
    float4 xr0_a, xr0_b, xr0_c, xr0_d;   // parity-0 in-flight raw x
    float4 xr1_a, xr1_b, xr1_c, xr1_d;   // parity-1
    {
        const float* xp = xgb + EE;      // x[1] -> consumed end of step 0
        xr1_a = ((const float4*)xp)[0];
        xr1_b = ((const float4*)(xp + 4))[0];
        xr1_c = ((const float4*)(xp + 32))[0];
        xr1_d = ((const float4*)(xp + 36))[0];
    }
    xr0_a = xr0_b = xr0_c = xr0_d = make_float4(0.f, 0.f, 0.f, 0.f);
    float dtc = dpt[0];
    float dr0v = 0.f, dr1v = dpt[1];

    float cst[4]  = {0.f, 0.f, 0.f, 0.f};
    float hsum[4] = {0.f, 0.f, 0.f, 0.f};
    __syncthreads();

#define TLSTM_STEP(s, CUR, NXT)                                               \
    {                                                                         \
        const int s2 = ((s) + 2 < SS) ? (s) + 2 : SS - 1;                     \
        {                                                                     \
            const float* xp = xgb + (size_t)s2 * EE;                          \
            xr##CUR##_a = ((const float4*)xp)[0];                             \
            xr##CUR##_b = ((const float4*)(xp + 4))[0];                       \
            xr##CUR##_c = ((const float4*)(xp + 32))[0];                      \
            xr##CUR##_d = ((const float4*)(xp + 36))[0];                      \
            dr##CUR##v  = dpt[s2];                                            \
        }                                                                     \
        f32x4 a0  = {bs0.x, bs0.y, bs0.z, bs0.w};                             \
        f32x4 a1  = {bs1.x, bs1.y, bs1.z, bs1.w};                             \
        f32x4 a2  = {bs2.x, bs2.y, bs2.z, bs2.w};                             \
        f32x4 a3  = {bs3.x, bs3.y, bs3.z, bs3.w};                             \
        f32x4 adw = {bd4.x, bd4.y, bd4.z, bd4.w};                             \
        _Pragma("unroll")                                                     \
        for (int kk = 0; kk < 4; ++kk) {                                      \
            f16x8 hB = *(const f16x8*)&sh_h[CUR][roff + kk * 32];             \
            a0 = mfma16(wA[0][kk], hB, a0);                                   \
            a1 = mfma16(wA[1][kk], hB, a1);                                   \
            a2 = mfma16(wA[2][kk], hB, a2);                                   \
            a3 = mfma16(wA[3][kk], hB, a3);                                   \
            f16x8 cB = *(const f16x8*)&sh_c[CUR][roff + kk * 32];             \
            adw = mfma16(dA[kk], cB, adw);                                    \
        }                                                                     \
        a0 = mfma16(uA[0][0], xB0, a0);  a0 = mfma16(uA[0][1], xB1, a0);      \
        a1 = mfma16(uA[1][0], xB0, a1);  a1 = mfma16(uA[1][1], xB1, a1);      \
        a2 = mfma16(uA[2][0], xB0, a2);  a2 = mfma16(uA[2][1], xB1, a2);      \
        a3 = mfma16(uA[3][0], xB0, a3);  a3 = mfma16(uA[3][1], xB1, a3);      \
        f16x4 hv4, cv4;                                                       \
        {                                                                     \
            const float dm1 = dtc - 1.0f;                                     \
            _Pragma("unroll")                                                 \
            for (int i = 0; i < 4; ++i) {                                     \
                float cdot = tanh_f(adw[i]);                                  \
                float cadj = __builtin_fmaf(cdot, dm1, cst[i]);               \
                float fg = sigm_f(a0[i]);                                     \
                float ig = sigm_f(a1[i]);                                     \
                float og = sigm_f(a2[i]);                                     \
                float cg = sigm_f(a3[i]);                                     \
                float cn = __builtin_fmaf(fg, cadj, ig * cg);                 \
                float hn = og * tanh_f(cn);                                   \
                cst[i]  = cn;                                                 \
                hsum[i] += hn;                                                \
                hv4[i] = (_Float16)hn;                                        \
                cv4[i] = (_Float16)cn;                                        \
            }                                                                 \
        }                                                                     \
        *(f16x4*)&sh_h[NXT][woff] = hv4;   /* one b64 write */                \
        *(f16x4*)&sh_c[NXT][woff] = cv4;                                      \
        xB0 = pack8(xr##NXT##_a, xr##NXT##_b);                                \
        xB1 = pack8(xr##NXT##_c, xr##NXT##_d);                                \
        dtc = dr##NXT##v;                                                     \
        __syncthreads();                                                      \
    }

    for (int s = 0; s < SS; s += 2) {
        TLSTM_STEP(s,     0, 1)
        TLSTM_STEP(s + 1, 1, 0)
    }
#undef TLSTM_STEP

    // ---- epilogue: out[b] = sum_u hsum[u,b]*W_out[u] + S*b_out ----
    {
        float p = hsum[0] * wo4.x + hsum[1] * wo4.y +
                  hsum[2] * wo4.z + hsum[3] * wo4.w;
        sh_red[w][Q][bcol] = p;
    }
    __syncthreads();
    if (t < MB) {
        const float* r = (const float*)sh_red;
        float acc = 0.f;
        #pragma unroll
        for (int j = 0; j < 32; ++j) acc += r[j * 16 + t];
        out[b0 + t] = acc + (float)SS * b_out[0];
    }
}

extern "C" void kernel_launch(void* const* d_in, const int* in_sizes, int n_in,
                              void* d_out, int out_size, void* d_ws, size_t ws_size,
                              hipStream_t stream) {
    const float* inputs        = (const float*)d_in[0];
    const float* time_interval = (const float*)d_in[1];
    const float* W_all         = (const float*)d_in[2];
    const float* b_all         = (const float*)d_in[3];
    const float* U_all         = (const float*)d_in[4];
    const float* b_u           = (const float*)d_in[5];
    const float* W_d           = (const float*)d_in[6];
    const float* b_d           = (const float*)d_in[7];
    const float* W_out         = (const float*)d_in[8];
    const float* b_out         = (const float*)d_in[9];
    float* out = (float*)d_out;

    tlstm_mfma3_kernel<<<dim3(NB), dim3(512), 0, stream>>>(
        inputs, time_interval, W_all, b_all, U_all, b_u,
        W_d, b_d, W_out, b_out, out);
}

// Round 6
// 2306.554 us; speedup vs baseline: 1.2785x; 1.2785x over previous
//
#include <hip/hip_runtime.h>
#include <math.h>

#define BB 256
#define SS 2048
#define EE 64
#define HH 128

typedef _Float16 half2_t __attribute__((ext_vector_type(2)));
typedef unsigned int uint2v __attribute__((ext_vector_type(2)));

#if defined(__has_builtin)
#if __has_builtin(__builtin_amdgcn_fdot2)
#define HAVE_FDOT2 1
#endif
#if __has_builtin(__builtin_amdgcn_update_dpp)
#define HAVE_DPP 1
#endif
#if __has_builtin(__builtin_amdgcn_permlane32_swap)
#define HAVE_PL32 1
#endif
#if __has_builtin(__builtin_amdgcn_exp2f)
#define EXP2F(x) __builtin_amdgcn_exp2f(x)
#else
#define EXP2F(x) exp2f(x)
#endif
#if __has_builtin(__builtin_amdgcn_rcpf)
#define RCPF(x) __builtin_amdgcn_rcpf(x)
#else
#define RCPF(x) (1.0f / (x))
#endif
#else
#define EXP2F(x) exp2f(x)
#define RCPF(x) (1.0f / (x))
#endif

__device__ __forceinline__ float dot2f(half2_t a, half2_t b, float c) {
#ifdef HAVE_FDOT2
    return __builtin_amdgcn_fdot2(a, b, c, false);
#else
    return c + (float)a.x * (float)b.x + (float)a.y * (float)b.y;
#endif
}

// quad_perm DPP: lane xor 1 / xor 2 within each quad (VALU pipe, no DS traffic)
__device__ __forceinline__ float dpp_xor1(float v) {
#ifdef HAVE_DPP
    int r = __builtin_amdgcn_update_dpp(0, __float_as_int(v), 0xB1, 0xF, 0xF, true);
    return __int_as_float(r);
#else
    return __shfl_xor(v, 1, 64);
#endif
}
__device__ __forceinline__ float dpp_xor2(float v) {
#ifdef HAVE_DPP
    int r = __builtin_amdgcn_update_dpp(0, __float_as_int(v), 0x4E, 0xF, 0xF, true);
    return __int_as_float(r);
#else
    return __shfl_xor(v, 2, 64);
#endif
}
// row_ror:8 (0x120+8): rotate each 16-lane row by 8 == lane xor 8 involution
__device__ __forceinline__ float dpp_ror8(float v) {
#ifdef HAVE_DPP
    int r = __builtin_amdgcn_update_dpp(0, __float_as_int(v), 0x128, 0xF, 0xF, true);
    return __int_as_float(r);
#else
    return __shfl_xor(v, 8, 64);
#endif
}

// Cross-half exchange (lane l <-> l^32):
// lower lanes receive partner's `a`, upper lanes receive partner's `b`.
__device__ __forceinline__ float xhalf_recv(float a, float b, bool lower) {
#ifdef HAVE_PL32
    uint2v r = __builtin_amdgcn_permlane32_swap(__float_as_int(a), __float_as_int(b), false, false);
    return __int_as_float((int)(lower ? r.y : r.x));
#else
    float ra = __shfl_xor(a, 32, 64);
    float rb = __shfl_xor(b, 32, 64);
    return lower ? ra : rb;
#endif
}

__device__ __forceinline__ float sigm_f(float x) {
    float e = EXP2F(-1.442695041f * x);
    return RCPF(1.0f + e);
}
__device__ __forceinline__ float tanh_f(float x) {
    float e = EXP2F(2.885390082f * x);
    return 1.0f - 2.0f * RCPF(1.0f + e);
}

// One block per batch element, 1024 threads (16 waves, 1 block/CU, 4 waves/SIMD).
// 16-lane group = lanes with fixed (bit2, bit4); varying bits {0,1 (m), 3 (q8),
// 5 (lh)} index the k-slice owner L = m + 4*q8 + 8*lh in [0,16). Group handles
// units u0 = 8*wv + 2*gidx (+lh), gidx = bit2 + 2*bit4.
// Per lane: 56 half2 of weights (HALF of the 512-thread variant -> whole live
// set fits the hard 128-VGPR cap of a 1024-thread block: no AGPR shuttling),
// 56 v_dot2/step, reduce-scatter via DPP xor1/xor2 + row_ror:8 (xor8) +
// permlane32_swap (xor32), quad-distributed activations (1 sigmoid/lane),
// f32 c-state register-resident at m==0 lanes.
__global__ __launch_bounds__(1024, 4) void tlstm_fused16_kernel(
    const float* __restrict__ inputs,        // [B,S,E]
    const float* __restrict__ time_interval, // [B,S]
    const float* __restrict__ W_all,         // [4H,H]
    const float* __restrict__ b_all,         // [4H]
    const float* __restrict__ U_all,         // [4H,E]
    const float* __restrict__ b_u,           // [4H]
    const float* __restrict__ W_d,           // [H,H]
    const float* __restrict__ b_d,           // [H]
    const float* __restrict__ W_out,         // [1,H]
    const float* __restrict__ b_out,         // [1]
    float* __restrict__ out)                 // [B]
{
    const int b  = blockIdx.x;
    const int t  = threadIdx.x;
    const int l  = t & 63;
    const int wv = t >> 6;            // wave 0..15
    const int m  = l & 3;             // lane within quad
    const int q8 = (l >> 3) & 1;      // quad-pair bit (xor8 partner dim)
    const int lh = (l >> 5) & 1;      // wave half (xor32 partner dim)
    const int gidx = ((l >> 2) & 1) + 2 * ((l >> 4) & 1);   // group id in wave
    const int L  = m + 4 * q8 + 8 * lh;   // k-slice owner 0..15, slice [8L,8L+8)
    const bool lower = (lh == 0);

    const int un_base = 8 * wv + 2 * gidx;
    const int my_un   = un_base + lh;

    __shared__ __align__(16) _Float16 sh_h[2][HH];
    __shared__ __align__(16) _Float16 sh_c[2][HH];
    __shared__ __align__(16) _Float16 sh_x[2][EE];
    __shared__ float sh_red[HH];

    // ---- weights into registers (fp16-packed): 56 half2 / lane ----
    // wg[q+4uu][*]: W_all row (un_base+uu)+128q, cols [8L,8L+8)  (4 half2)
    // ug[q+4uu][*]: U_all same rows, cols [4L,4L+4)              (2 half2)
    // wd[uu][*]:    W_d row (un_base+uu), cols [8L,8L+8)         (4 half2)
    half2_t wg[8][4];
    half2_t ug[8][2];
    half2_t wd[2][4];
    float   biasr, bd_r, wout_r;
    {
        #pragma unroll
        for (int uu = 0; uu < 2; ++uu) {
            #pragma unroll
            for (int q = 0; q < 4; ++q) {
                const int j   = q + 4 * uu;
                const int row = (un_base + uu) + 128 * q;
                const float4* pw = (const float4*)(W_all + (size_t)row * HH + 8 * L);
                #pragma unroll
                for (int i = 0; i < 2; ++i) {
                    float4 v = pw[i];
                    half2_t h0, h1;
                    h0.x = (_Float16)v.x; h0.y = (_Float16)v.y;
                    h1.x = (_Float16)v.z; h1.y = (_Float16)v.w;
                    wg[j][2*i]   = h0;
                    wg[j][2*i+1] = h1;
                }
                const float4* pu = (const float4*)(U_all + (size_t)row * EE + 4 * L);
                {
                    float4 v = pu[0];
                    half2_t h0, h1;
                    h0.x = (_Float16)v.x; h0.y = (_Float16)v.y;
                    h1.x = (_Float16)v.z; h1.y = (_Float16)v.w;
                    ug[j][0] = h0;
                    ug[j][1] = h1;
                }
            }
            const int rowd = un_base + uu;
            const float4* pd = (const float4*)(W_d + (size_t)rowd * HH + 8 * L);
            #pragma unroll
            for (int i = 0; i < 2; ++i) {
                float4 v = pd[i];
                half2_t h0, h1;
                h0.x = (_Float16)v.x; h0.y = (_Float16)v.y;
                h1.x = (_Float16)v.z; h1.y = (_Float16)v.w;
                wd[uu][2*i]   = h0;
                wd[uu][2*i+1] = h1;
            }
        }
        const int row_own = my_un + 128 * m;
        biasr  = b_all[row_own] + b_u[row_own];
        bd_r   = b_d[my_un];
        wout_r = W_out[my_un];
    }

    const float* xg   = inputs + (size_t)b * SS * EE;
    const float* drow = time_interval + (size_t)b * SS;

    // ---- balanced x-prefetch: lanes 0-3 of wave w stage x[4w..4w+4) ----
    const bool xact = (l < 4);
    const int  xidx = 4 * wv + (l & 3);

    // ---- loop-invariant LDS addresses ----
    const _Float16* hb0 = &sh_h[0][8 * L];
    const _Float16* hb1 = &sh_h[1][8 * L];
    const _Float16* cb0 = &sh_c[0][8 * L];
    const _Float16* cb1 = &sh_c[1][8 * L];
    const _Float16* xr0 = &sh_x[0][4 * L];
    const _Float16* xr1 = &sh_x[1][4 * L];
    _Float16* wxp0 = &sh_x[0][xidx];
    _Float16* wxp1 = &sh_x[1][xidx];
    _Float16* wcp0 = &sh_c[0][my_un];
    _Float16* wcp1 = &sh_c[1][my_un];
    _Float16* whp0 = &sh_h[0][my_un];
    _Float16* whp1 = &sh_h[1][my_un];

    // ---- prologue: zero state buffer 0, prime x/dt pipelines ----
    if (t < HH) { sh_h[0][t] = (_Float16)0.f; sh_c[0][t] = (_Float16)0.f; }
    float xcv = 0.f, xld = 0.f;
    if (xact) {
        sh_x[0][xidx] = (_Float16)xg[xidx];     // x[0]
        xcv = xg[EE + xidx];                     // x[1]
        xld = xg[2 * EE + xidx];                 // x[2]
    }
    float dv0 = drow[0], dv1 = drow[1], dv2 = drow[2];
    float hsum   = 0.f;
    float c_keep = 0.f;   // valid at m==0 lanes (q8 copies duplicate)
    __syncthreads();

#define TLSTM_STEP(s, CUR, NXT)                                               \
    {                                                                         \
        if (xact) {                                                           \
            *wxp##NXT = (_Float16)xcv;                                        \
            xcv = xld;                                                        \
            const int s3 = ((s) + 3 < SS) ? (s) + 3 : SS - 1;                 \
            xld = xg[(size_t)s3 * EE + xidx];                                 \
        }                                                                     \
        float4 hv4, cv4f;                                                     \
        float2 xv2;                                                           \
        {                                                                     \
            hv4  = *(const float4*)hb##CUR;                                   \
            cv4f = *(const float4*)cb##CUR;                                   \
            xv2  = *(const float2*)xr##CUR;                                   \
        }                                                                     \
        float a[8] = {0.f,0.f,0.f,0.f,0.f,0.f,0.f,0.f};                       \
        float ad0 = 0.f, ad1 = 0.f;                                           \
        {                                                                     \
            const half2_t* hh = (const half2_t*)&hv4;                         \
            _Pragma("unroll")                                                 \
            for (int p = 0; p < 4; ++p) {                                     \
                _Pragma("unroll")                                             \
                for (int j = 0; j < 8; ++j)                                   \
                    a[j] = dot2f(wg[j][p], hh[p], a[j]);                      \
            }                                                                 \
            const half2_t* xh = (const half2_t*)&xv2;                         \
            _Pragma("unroll")                                                 \
            for (int p = 0; p < 2; ++p) {                                     \
                _Pragma("unroll")                                             \
                for (int j = 0; j < 8; ++j)                                   \
                    a[j] = dot2f(ug[j][p], xh[p], a[j]);                      \
            }                                                                 \
            const half2_t* ch = (const half2_t*)&cv4f;                        \
            _Pragma("unroll")                                                 \
            for (int p = 0; p < 4; ++p) {                                     \
                ad0 = dot2f(wd[0][p], ch[p], ad0);                            \
                ad1 = dot2f(wd[1][p], ch[p], ad1);                            \
            }                                                                 \
        }                                                                     \
        /* reduce-scatter over 16 k-lanes: xor1,xor2 (quad), xor8 (ror8), */  \
        /* xor32 (permlane). Lane ends owning gate m of unit lh. */           \
        const bool oddl = (m & 1) != 0;                                       \
        const bool bit2 = (m & 2) != 0;                                       \
        float s0, s1, s2, s3v;                                                \
        {                                                                     \
            float snd, r;                                                     \
            snd = oddl ? a[0] : a[1]; r = dpp_xor1(snd);                      \
            s0 = (oddl ? a[1] : a[0]) + r;                                    \
            snd = oddl ? a[2] : a[3]; r = dpp_xor1(snd);                      \
            s1 = (oddl ? a[3] : a[2]) + r;                                    \
            snd = oddl ? a[4] : a[5]; r = dpp_xor1(snd);                      \
            s2 = (oddl ? a[5] : a[4]) + r;                                    \
            snd = oddl ? a[6] : a[7]; r = dpp_xor1(snd);                      \
            s3v = (oddl ? a[7] : a[6]) + r;                                   \
        }                                                                     \
        float u0v, u1v;                                                       \
        {                                                                     \
            float snd, r;                                                     \
            snd = bit2 ? s0 : s1; r = dpp_xor2(snd);                          \
            u0v = (bit2 ? s1 : s0) + r;                                       \
            snd = bit2 ? s2 : s3v; r = dpp_xor2(snd);                         \
            u1v = (bit2 ? s3v : s2) + r;                                      \
        }                                                                     \
        u0v += dpp_ror8(u0v);                                                 \
        u1v += dpp_ror8(u1v);                                                 \
        float g = (lower ? u0v : u1v) + xhalf_recv(u0v, u1v, lower);          \
        /* W_d dot: full 16-lane sum, broadcast within quad */                \
        float dd = (lower ? ad0 : ad1) + xhalf_recv(ad0, ad1, lower);         \
        dd += dpp_ror8(dd);                                                   \
        dd += dpp_xor2(dd);                                                   \
        dd += dpp_xor1(dd);                                                   \
        /* lane-distributed activations: m=0:f 1:i 2:o(+cs1) 3:ct */          \
        float sg  = sigm_f(g + biasr);                                        \
        float cs1 = tanh_f(bd_r + dd);                                        \
        float sel1 = (m == 2) ? cs1 : sg;                                     \
        float sh2  = dpp_xor2(sel1);  /* m0<-cs1, m1<-sig(ct) */              \
        float sh2b = dpp_xor2(sg);    /* m0<-sig(o)           */              \
        float dm1  = dv0 - 1.0f;                                              \
        float cadj = __builtin_fmaf(sh2, dm1, c_keep);   /* m0: c+cs1*(d-1) */\
        float prod = sg * (oddl ? sh2 : cadj); /* m0: f*cadj, m1: i*ct */     \
        float cn   = prod + dpp_xor1(prod);    /* m0,m1: full c_new */        \
        float hn   = sh2b * tanh_f(cn);        /* m0: o*tanh(c_new) */        \
        c_keep = cn;                                                          \
        hsum  += hn;                                                          \
        if ((l & 11) == 0) {   /* m==0 && q8==0: one writer per unit */       \
            *wcp##NXT = (_Float16)cn;                                         \
            *whp##NXT = (_Float16)hn;                                         \
        }                                                                     \
        dv0 = dv1; dv1 = dv2;                                                 \
        const int sd = ((s) + 3 < SS) ? (s) + 3 : SS - 1;                     \
        dv2 = drow[sd];                                                       \
        __syncthreads();                                                      \
    }

    for (int s = 0; s < SS; s += 2) {
        TLSTM_STEP(s,     0, 1)
        TLSTM_STEP(s + 1, 1, 0)
    }
#undef TLSTM_STEP

    // ---- output epilogue: out[b] = (sum_s h_s) . W_out + S*b_out ----
    if ((l & 11) == 0) sh_red[my_un] = hsum * wout_r;
    __syncthreads();
    if (t == 0) {
        float acc = 0.f;
        for (int i = 0; i < HH; ++i) acc += sh_red[i];
        out[b] = acc + (float)SS * b_out[0];
    }
}

extern "C" void kernel_launch(void* const* d_in, const int* in_sizes, int n_in,
                              void* d_out, int out_size, void* d_ws, size_t ws_size,
                              hipStream_t stream) {
    const float* inputs        = (const float*)d_in[0];
    const float* time_interval = (const float*)d_in[1];
    const float* W_all         = (const float*)d_in[2];
    const float* b_all         = (const float*)d_in[3];
    const float* U_all         = (const float*)d_in[4];
    const float* b_u           = (const float*)d_in[5];
    const float* W_d           = (const float*)d_in[6];
    const float* b_d           = (const float*)d_in[7];
    const float* W_out         = (const float*)d_in[8];
    const float* b_out         = (const float*)d_in[9];
    float* out = (float*)d_out;

    tlstm_fused16_kernel<<<dim3(BB), dim3(1024), 0, stream>>>(
        inputs, time_interval, W_all, b_all, U_all, b_u,
        W_d, b_d, W_out, b_out, out);
}

// Round 7
// 1524.415 us; speedup vs baseline: 1.9345x; 1.5131x over previous
//
#include <hip/hip_runtime.h>
#include <math.h>

#define BB 256
#define SS 2048
#define EE 64
#define HH 128

typedef _Float16 f16x8 __attribute__((ext_vector_type(8)));
typedef float f32x4 __attribute__((ext_vector_type(4)));

#if defined(__has_builtin)
#if __has_builtin(__builtin_amdgcn_exp2f)
#define EXP2F(x) __builtin_amdgcn_exp2f(x)
#else
#define EXP2F(x) exp2f(x)
#endif
#if __has_builtin(__builtin_amdgcn_rcpf)
#define RCPF(x) __builtin_amdgcn_rcpf(x)
#else
#define RCPF(x) (1.0f / (x))
#endif
#else
#define EXP2F(x) exp2f(x)
#define RCPF(x) (1.0f / (x))
#endif

__device__ __forceinline__ float sigm_f(float x) {
    float e = EXP2F(-1.442695041f * x);
    return RCPF(1.0f + e);
}
__device__ __forceinline__ float tanh_f(float x) {
    float e = EXP2F(2.885390082f * x);
    return 1.0f - 2.0f * RCPF(1.0f + e);
}

__device__ __forceinline__ f32x4 mfma16(f16x8 a, f16x8 b, f32x4 c) {
    return __builtin_amdgcn_mfma_f32_16x16x32_f16(a, b, c, 0, 0, 0);
}

__device__ __forceinline__ f16x8 pack8(float4 a, float4 b) {
    f16x8 r;
    r[0] = (_Float16)a.x; r[1] = (_Float16)a.y;
    r[2] = (_Float16)a.z; r[3] = (_Float16)a.w;
    r[4] = (_Float16)b.x; r[5] = (_Float16)b.y;
    r[6] = (_Float16)b.z; r[7] = (_Float16)b.w;
    return r;
}

// One block per batch (256 blocks = all CUs), 512 threads, 8 waves.
// Wave w owns units [16w, 16w+16). Dots run on the MATRIX pipe via
// replicated-A mfma: A[r][k] = state[32*kk + k] for ALL 16 rows (a 4-address
// broadcast ds_read_b128), B[k][c] = W[unit 16w+c][32*kk + k] (weights pinned
// in registers/AGPRs -- MFMA reads AGPRs natively, zero copy cost). Chaining
// kk gives D[*][c] = full dot for unit c, IDENTICAL in all 4 lanes of column
// c: the gate values land pre-distributed, so the entire DPP reduce-scatter
// tree of the VALU kernel is deleted. Per wave/step: 10 broadcast ds_read_b128
// + 28 mfma + ~45-inst lane-local epilogue (4-way redundant, free).
// f32 cell state stays in registers (each lane's unit fixed across steps).
__global__ __launch_bounds__(512, 2) void tlstm_hyb_kernel(
    const float* __restrict__ inputs,        // [B,S,E]
    const float* __restrict__ time_interval, // [B,S]
    const float* __restrict__ W_all,         // [4H,H]
    const float* __restrict__ b_all,         // [4H]
    const float* __restrict__ U_all,         // [4H,E]
    const float* __restrict__ b_u,           // [4H]
    const float* __restrict__ W_d,           // [H,H]
    const float* __restrict__ b_d,           // [H]
    const float* __restrict__ W_out,         // [1,H]
    const float* __restrict__ b_out,         // [1]
    float* __restrict__ out)                 // [B]
{
    const int b    = blockIdx.x;
    const int t    = threadIdx.x;
    const int l    = t & 63;
    const int wv   = t >> 6;        // wave 0..7
    const int col  = l & 15;        // B/C column = unit-within-tile
    const int Q    = l >> 4;        // lane quarter -> k-subrange [8Q, 8Q+8)
    const int unit = 16 * wv + col; // this lane's unit

    __shared__ __align__(16) _Float16 sh_h[2][HH];
    __shared__ __align__(16) _Float16 sh_c[2][HH];
    __shared__ __align__(16) _Float16 sh_x[2][EE];
    __shared__ float sh_red[HH];

    // ---- loop-invariant weights as B-fragments (f16; AGPR-friendly) ----
    // B[k][c]: lane holds B[k = 8Q + j][c = col] = W_row(unit)[32*kk + 8Q + j]
    f16x8 wB[4][4];   // [gate][k-chunk]
    f16x8 uB[4][2];
    f16x8 dB[4];
    float bsum[4];
    #pragma unroll
    for (int q = 0; q < 4; ++q) {
        const int row = q * HH + unit;
        const float* wp = W_all + (size_t)row * HH + 8 * Q;
        #pragma unroll
        for (int kk = 0; kk < 4; ++kk) {
            const float4* p = (const float4*)(wp + kk * 32);
            wB[q][kk] = pack8(p[0], p[1]);
        }
        const float* up = U_all + (size_t)row * EE + 8 * Q;
        #pragma unroll
        for (int kk = 0; kk < 2; ++kk) {
            const float4* p = (const float4*)(up + kk * 32);
            uB[q][kk] = pack8(p[0], p[1]);
        }
        bsum[q] = b_all[row] + b_u[row];
    }
    {
        const float* dp = W_d + (size_t)unit * HH + 8 * Q;
        #pragma unroll
        for (int kk = 0; kk < 4; ++kk) {
            const float4* p = (const float4*)(dp + kk * 32);
            dB[kk] = pack8(p[0], p[1]);
        }
    }
    const float bd_r   = b_d[unit];
    const float wout_r = W_out[unit];

    const float* xg   = inputs + (size_t)b * SS * EE;
    const float* drow = time_interval + (size_t)b * SS;

    // balanced x staging: lanes 0-7 of wave w handle x[8w .. 8w+8)
    const bool xact = (l < 8);
    const int  xidx = 8 * wv + l;   // valid when xact

    // ---- prologue: zero state buf0, prime x/dt pipelines ----
    if (t < HH) { sh_h[0][t] = (_Float16)0.f; sh_c[0][t] = (_Float16)0.f; }
    float xcv = 0.f, xld = 0.f;
    if (xact) {
        sh_x[0][xidx] = (_Float16)xg[xidx];   // x[0]
        xcv = xg[EE + xidx];                   // x[1]
        xld = xg[2 * EE + xidx];               // x[2]
    }
    float dv0 = drow[0], dv1 = drow[1], dv2 = drow[2];
    float c_keep = 0.f;     // f32 cell state for `unit` (4-way redundant per quad-col)
    float hsum   = 0.f;
    __syncthreads();

#define TLSTM_STEP(s, CUR, NXT)                                               \
    {                                                                         \
        if (xact) {                                                           \
            sh_x[NXT][xidx] = (_Float16)xcv;                                  \
            xcv = xld;                                                        \
            const int s3 = ((s) + 3 < SS) ? (s) + 3 : SS - 1;                 \
            xld = xg[(size_t)s3 * EE + xidx];                                 \
        }                                                                     \
        f32x4 a0  = {0.f, 0.f, 0.f, 0.f};                                     \
        f32x4 a1  = {0.f, 0.f, 0.f, 0.f};                                     \
        f32x4 a2  = {0.f, 0.f, 0.f, 0.f};                                     \
        f32x4 a3  = {0.f, 0.f, 0.f, 0.f};                                     \
        f32x4 adw = {0.f, 0.f, 0.f, 0.f};                                     \
        _Pragma("unroll")                                                     \
        for (int kk = 0; kk < 4; ++kk) {                                      \
            f16x8 hA = *(const f16x8*)&sh_h[CUR][kk * 32 + 8 * Q];            \
            f16x8 cA = *(const f16x8*)&sh_c[CUR][kk * 32 + 8 * Q];            \
            a0  = mfma16(hA, wB[0][kk], a0);                                  \
            a1  = mfma16(hA, wB[1][kk], a1);                                  \
            a2  = mfma16(hA, wB[2][kk], a2);                                  \
            a3  = mfma16(hA, wB[3][kk], a3);                                  \
            adw = mfma16(cA, dB[kk], adw);                                    \
        }                                                                     \
        _Pragma("unroll")                                                     \
        for (int kk = 0; kk < 2; ++kk) {                                      \
            f16x8 xA = *(const f16x8*)&sh_x[CUR][kk * 32 + 8 * Q];            \
            a0 = mfma16(xA, uB[0][kk], a0);                                   \
            a1 = mfma16(xA, uB[1][kk], a1);                                   \
            a2 = mfma16(xA, uB[2][kk], a2);                                   \
            a3 = mfma16(xA, uB[3][kk], a3);                                   \
        }                                                                     \
        {                                                                     \
            float cdot = tanh_f(adw[0] + bd_r);                               \
            float cadj = __builtin_fmaf(cdot, dv0 - 1.0f, c_keep);            \
            float fg = sigm_f(a0[0] + bsum[0]);                               \
            float ig = sigm_f(a1[0] + bsum[1]);                               \
            float og = sigm_f(a2[0] + bsum[2]);                               \
            float cg = sigm_f(a3[0] + bsum[3]);                               \
            float cn = __builtin_fmaf(fg, cadj, ig * cg);                     \
            float hn = og * tanh_f(cn);                                       \
            c_keep = cn;                                                      \
            hsum  += hn;                                                      \
            if (l < 16) {   /* Q==0 lane of each column writes its unit */    \
                sh_c[NXT][unit] = (_Float16)cn;                               \
                sh_h[NXT][unit] = (_Float16)hn;                               \
            }                                                                 \
        }                                                                     \
        dv0 = dv1; dv1 = dv2;                                                 \
        const int sd = ((s) + 3 < SS) ? (s) + 3 : SS - 1;                     \
        dv2 = drow[sd];                                                       \
        __syncthreads();                                                      \
    }

    for (int s = 0; s < SS; s += 2) {
        TLSTM_STEP(s,     0, 1)
        TLSTM_STEP(s + 1, 1, 0)
    }
#undef TLSTM_STEP

    // ---- output epilogue: out[b] = (sum_s h_s) . W_out + S*b_out ----
    if (l < 16) sh_red[unit] = hsum * wout_r;
    __syncthreads();
    if (t == 0) {
        float acc = 0.f;
        for (int i = 0; i < HH; ++i) acc += sh_red[i];
        out[b] = acc + (float)SS * b_out[0];
    }
}

extern "C" void kernel_launch(void* const* d_in, const int* in_sizes, int n_in,
                              void* d_out, int out_size, void* d_ws, size_t ws_size,
                              hipStream_t stream) {
    const float* inputs        = (const float*)d_in[0];
    const float* time_interval = (const float*)d_in[1];
    const float* W_all         = (const float*)d_in[2];
    const float* b_all         = (const float*)d_in[3];
    const float* U_all         = (const float*)d_in[4];
    const float* b_u           = (const float*)d_in[5];
    const float* W_d           = (const float*)d_in[6];
    const float* b_d           = (const float*)d_in[7];
    const float* W_out         = (const float*)d_in[8];
    const float* b_out         = (const float*)d_in[9];
    float* out = (float*)d_out;

    tlstm_hyb_kernel<<<dim3(BB), dim3(512), 0, stream>>>(
        inputs, time_interval, W_all, b_all, U_all, b_u,
        W_d, b_d, W_out, b_out, out);
}